// Round 1
// baseline (208.918 us; speedup 1.0000x reference)
//
#include <hip/hip_runtime.h>
#include <math.h>

#define SDIM 4096
#define DIN  1024
#define DOUT 64
#define BB   4
#define MTOT (BB * SDIM)   // 16384 rows
#define SMAX 12.0f         // fixed softmax max (log2 domain); true max ~8

typedef __attribute__((ext_vector_type(8))) short short8;    // 8 x bf16
typedef __attribute__((ext_vector_type(4))) float floatx4;
typedef __attribute__((ext_vector_type(16))) float floatx16;

static __device__ __forceinline__ unsigned short f2bf(float f) {
  union { float f; unsigned int u; } v; v.f = f;
  unsigned int r = v.u + 0x7fffu + ((v.u >> 16) & 1u);
  return (unsigned short)(r >> 16);
}

static __device__ __forceinline__ floatx4 mfma16(short8 a, short8 b, floatx4 c) {
  return __builtin_amdgcn_mfma_f32_16x16x32_bf16(a, b, c, 0, 0, 0);
}
static __device__ __forceinline__ floatx16 mfma32(short8 a, short8 b, floatx16 c) {
  return __builtin_amdgcn_mfma_f32_32x32x16_bf16(a, b, c, 0, 0, 0);
}
// pack two f32 -> one dword of 2 bf16 (lo = src0)
static __device__ __forceinline__ unsigned int cvtpk(float lo, float hi) {
  unsigned int r;
  asm("v_cvt_pk_bf16_f32 %0, %1, %2" : "=v"(r) : "v"(lo), "v"(hi));
  return r;
}

// ---------------------------------------------------------------------------
// W -> bf16:  wb[o][k].  q scale folds 1/sqrt(64) AND log2(e) (exp2 domain).
// ---------------------------------------------------------------------------
__global__ __launch_bounds__(256) void wcvt_kernel(
    const float* __restrict__ Wq, const float* __restrict__ Wk,
    const float* __restrict__ Wv, unsigned short* __restrict__ wb) {
  const int idx  = blockIdx.x * 256 + threadIdx.x;
  const int flat = idx * 4;
  const int m    = flat >> 16;
  const int off  = flat & 65535;
  const float* src = (m == 0) ? Wq : (m == 1) ? Wk : Wv;
  const float  s   = (m == 0) ? 0.125f * 1.44269504f : 1.0f;
  float4 v = *(const float4*)(src + off);
  ushort4 u;
  u.x = f2bf(v.x * s); u.y = f2bf(v.y * s);
  u.z = f2bf(v.z * s); u.w = f2bf(v.w * s);
  *(ushort4*)(wb + (size_t)m * 65536 + off) = u;
}

// ---------------------------------------------------------------------------
// Projection, bf16 MFMA: out = x(16384x1024) @ wb^T(1024x192).
// 512 blocks x 32-row M-tiles, BK=128 -> 8 K-iters; x prefetch flies during
// the 24-MFMA compute phase. (unchanged — proven)
// ---------------------------------------------------------------------------
__global__ __launch_bounds__(256) void proj_kernel(
    const float* __restrict__ x, const unsigned short* __restrict__ wb,
    unsigned short* __restrict__ qk, unsigned short* __restrict__ vt) {
  __shared__ short Xs[32][136];   // 32 rows x 128 k bf16, stride 136 (272 B)
  __shared__ short Vl[64][40];    // V^T tile [d][seq_local]

  const int tid  = threadIdx.x;
  const int wave = tid >> 6;
  const int lane = tid & 63;
  const int quad = lane >> 4;
  const int l16  = lane & 15;
  const int row0 = blockIdx.x * 32;

  floatx4 acc[2][3];
#pragma unroll
  for (int i = 0; i < 2; i++)
#pragma unroll
    for (int j = 0; j < 3; j++) acc[i][j] = floatx4{0, 0, 0, 0};

  const int sr = tid >> 3;          // staging row 0..31
  const int sc = (tid & 7) * 16;    // staging col (floats) {0,16,...,112}

  float4 xa[4];
  {
    const float* xp = x + (size_t)(row0 + sr) * DIN + sc;
#pragma unroll
    for (int i = 0; i < 4; i++) xa[i] = *(const float4*)(xp + i * 4);
  }

  for (int k0 = 0; k0 < DIN; k0 += 128) {
    __syncthreads();
    short8 s0, s1;
#pragma unroll
    for (int i = 0; i < 4; i++) {
      s0[i]     = f2bf(xa[0][i]); s0[i + 4] = f2bf(xa[1][i]);
      s1[i]     = f2bf(xa[2][i]); s1[i + 4] = f2bf(xa[3][i]);
    }
    *(short8*)&Xs[sr][sc]     = s0;
    *(short8*)&Xs[sr][sc + 8] = s1;
    __syncthreads();

    if (k0 + 128 < DIN) {
      const float* xp = x + (size_t)(row0 + sr) * DIN + (k0 + 128) + sc;
#pragma unroll
      for (int i = 0; i < 4; i++) xa[i] = *(const float4*)(xp + i * 4);
    }

#pragma unroll
    for (int s = 0; s < 4; s++) {   // 4 k-steps of 32
      const short8 a0 = *(const short8*)&Xs[l16][s * 32 + quad * 8];
      const short8 a1 = *(const short8*)&Xs[16 + l16][s * 32 + quad * 8];
#pragma unroll
      for (int f = 0; f < 3; f++) {
        const int col = (wave * 3 + f) * 16 + l16;
        const short8 b =
            *(const short8*)(wb + (size_t)col * DIN + k0 + s * 32 + quad * 8);
        acc[0][f] = mfma16(a0, b, acc[0][f]);
        acc[1][f] = mfma16(a1, b, acc[1][f]);
      }
    }
  }

  // epilogue: C-layout frag (row = quad*4+r, col = f*16+l16)
#pragma unroll
  for (int rr = 0; rr < 2; rr++)
#pragma unroll
    for (int f = 0; f < 3; f++) {
      const int col  = (wave * 3 + f) * 16 + l16;
      const int lrow = rr * 16 + quad * 4;   // + r
      if (col < 64) {
#pragma unroll
        for (int r = 0; r < 4; r++)
          qk[(size_t)(row0 + lrow + r) * 64 + col] = f2bf(acc[rr][f][r]);
      } else if (col < 128) {
#pragma unroll
        for (int r = 0; r < 4; r++)
          qk[(size_t)MTOT * 64 + (size_t)(row0 + lrow + r) * 64 + (col - 64)] =
              f2bf(acc[rr][f][r]);
      } else {
        const int d = col - 128;
#pragma unroll
        for (int r = 0; r < 4; r++)
          Vl[d][lrow + r] = (short)f2bf(acc[rr][f][r]);
      }
    }
  __syncthreads();

  {
    const int d  = tid >> 2;
    const int j  = (tid & 3) * 8;
    const int bb = row0 >> 12;       // batch
    const int sb = row0 & 4095;      // seq offset within batch
    unsigned short* dst = vt + ((size_t)bb * 64 + d) * SDIM + sb + j;
    *(short8*)(dst) = *(const short8*)&Vl[d][j];
  }
}

// ---------------------------------------------------------------------------
// Flash attention, LDS-FREE / BARRIER-FREE. One wave owns 32 q-rows.
// 32x32x16 MFMAs; K/V/Q fragments loaded straight from global (L2-resident:
// K+V = 6 MB). Swapped QK^T (S^T = mfma(K, Q)) puts q on lane&31 -> softmax
// entirely in-register; P is redistributed into the PV A-fragment layout with
// 16 v_cvt_pk_bf16_f32 + 8 v_permlane32_swap_b32 (no LDS round-trip).
// Fixed-max exp2-domain softmax (SMAX in the MFMA C-init) kept from R8.
// Per-wave causal key-limit (no barriers -> no block-uniform bound needed).
// Block swizzle: same (b, key-chunk) => same bid mod 8 => same XCD L2.
// ---------------------------------------------------------------------------
__global__ __launch_bounds__(256) void attn_kernel(
    const unsigned short* __restrict__ qk, const unsigned short* __restrict__ vt,
    float* __restrict__ po, float* __restrict__ pml, int C, int chunk_keys) {
  const int tid  = threadIdx.x;
  const int wave = tid >> 6;
  const int lane = tid & 63;
  const int l32  = lane & 31;
  const int hl   = lane >> 5;

  const int bx  = blockIdx.x;
  const int bcn = 4 * C;                 // blocks per q-band; bc in low bits
  const int qbo = bx / bcn;
  const int bc  = bx - qbo * bcn;        // (b, c): same bc -> same XCD (mod 8)
  const int b   = bc / C;
  const int c   = bc - b * C;
  const int qb  = 31 - qbo;              // deep-first

  const int k_start = c * chunk_keys;
  const int wq0 = qb * 128 + wave * 32;  // wave's first q row (within batch)
  if (k_start > wq0 + 31) return;        // wave-level causal inactivity
  const int k_lim = min(k_start + chunk_keys, (((wq0 + 31) >> 6) + 1) * 64);

  const unsigned short* qs = qk;
  const unsigned short* ks = qk + (size_t)MTOT * 64;

  // Q B-frags (col = l32 = q, k = hl*8+j), resident whole kernel
  short8 qf[4];
  {
    const unsigned short* qp = qs + ((size_t)(b * SDIM + wq0 + l32)) * 64 + hl * 8;
#pragma unroll
    for (int s = 0; s < 4; s++) qf[s] = *(const short8*)(qp + s * 16);
  }

  const unsigned short* kp =
      ks + ((size_t)(b * SDIM + k_start + l32)) * 64 + hl * 8;
  const unsigned short* vp =
      vt + ((size_t)(b * 64 + l32)) * SDIM + k_start + hl * 8;

  floatx16 o0, o1;
#pragma unroll
  for (int r = 0; r < 16; r++) { o0[r] = 0.f; o1[r] = 0.f; }
  float ls0 = 0.f, ls1 = 0.f, ls2 = 0.f, ls3 = 0.f;

  for (int k0 = k_start; k0 < k_lim; k0 += 64) {
    // K A-frags: row = l32 = key-local (sub*32+), k = d = hl*8+j
    short8 kf[8];
#pragma unroll
    for (int sub = 0; sub < 2; sub++)
#pragma unroll
      for (int s = 0; s < 4; s++)
        kf[sub * 4 + s] = *(const short8*)(kp + sub * 2048 + s * 16);

    // V B-frags: col = l32 = d-local (dh*32+), k = key = hl*8+j
    short8 vf[8];
#pragma unroll
    for (int dh = 0; dh < 2; dh++)
#pragma unroll
      for (int s = 0; s < 4; s++)
        vf[dh * 4 + s] = *(const short8*)(vp + dh * 32 * SDIM + s * 16);

    // ---- S^T - SMAX = K Q^T + (-SMAX) ----
    floatx16 s0, s1;
#pragma unroll
    for (int r = 0; r < 16; r++) { s0[r] = -SMAX; s1[r] = -SMAX; }
#pragma unroll
    for (int s = 0; s < 4; s++) s0 = mfma32(kf[s], qf[s], s0);
#pragma unroll
    for (int s = 0; s < 4; s++) s1 = mfma32(kf[4 + s], qf[s], s1);

    // causal mask: key = k0 + sub*32 + (r&3) + 8*(r>>2) + 4*hl; q = wq0 + l32
    if (k0 + 63 > wq0) {
      const int dq = k0 + hl * 4 - wq0 - l32;
#pragma unroll
      for (int r = 0; r < 16; r++) {
        const int kl = (r & 3) + 8 * (r >> 2);
        if (dq + kl > 0)      s0[r] = -INFINITY;
        if (dq + kl + 32 > 0) s1[r] = -INFINITY;
      }
    }

    // ---- p = exp2(s - SMAX); per-lane partial denominator ----
#pragma unroll
    for (int r = 0; r < 16; r++) { s0[r] = exp2f(s0[r]); s1[r] = exp2f(s1[r]); }
#pragma unroll
    for (int r = 0; r < 4; r++) {
      ls0 += s0[r]      + s1[r];
      ls1 += s0[r + 4]  + s1[r + 4];
      ls2 += s0[r + 8]  + s1[r + 8];
      ls3 += s0[r + 12] + s1[r + 12];
    }

    // ---- P (C-layout) -> PV A-frags via cvt_pk + permlane32_swap ----
    // A-frag step s: lane needs P[q=l32][key = s*16 + hl*8 + j], j=0..7.
    // dword d: x' of swap(cvtpk(p[r0],p[r0+1]), cvtpk(p[r0+4],p[r0+5])) etc.
    short8 pa[4];
#pragma unroll
    for (int sb = 0; sb < 2; sb++) {       // S^T sub-tile (keys sb*32..+31)
      const floatx16 sp = sb ? s1 : s0;
#pragma unroll
      for (int ss = 0; ss < 2; ss++) {     // 16-key step within sub-tile
        const int r0 = ss * 8;
        unsigned int x0 = cvtpk(sp[r0 + 0], sp[r0 + 1]);
        unsigned int y0 = cvtpk(sp[r0 + 4], sp[r0 + 5]);
        unsigned int x1 = cvtpk(sp[r0 + 2], sp[r0 + 3]);
        unsigned int y1 = cvtpk(sp[r0 + 6], sp[r0 + 7]);
        asm("v_permlane32_swap_b32 %0, %1" : "+v"(x0), "+v"(y0));
        asm("v_permlane32_swap_b32 %0, %1" : "+v"(x1), "+v"(y1));
        union { unsigned int u[4]; short8 s; } pu;
        pu.u[0] = x0; pu.u[1] = x1; pu.u[2] = y0; pu.u[3] = y1;
        pa[sb * 2 + ss] = pu.s;
      }
    }

    // ---- O += P V ----
#pragma unroll
    for (int s = 0; s < 4; s++) {
      o0 = mfma32(pa[s], vf[s],     o0);
      o1 = mfma32(pa[s], vf[4 + s], o1);
    }

    kp += 64 * 64;
    vp += 64;
  }

  // ---- denominator: combine chains + cross-half sum (q = l32 both halves) --
  float lsum = (ls0 + ls1) + (ls2 + ls3);
  lsum += __shfl_xor(lsum, 32);

  // ---- write partials; all chunks share the SMAX scale ----
  const size_t task = (size_t)((b * 32 + qb) * C + c);
  float* pot = po + task * 8192 + (size_t)wave * 32 * 64;
#pragma unroll
  for (int r = 0; r < 16; r++) {
    const int row = (r & 3) + 8 * (r >> 2) + 4 * hl;   // q-local 0..31
    pot[row * 64 + l32]      = o0[r];
    pot[row * 64 + 32 + l32] = o1[r];
  }
  if (hl == 0) pml[task * 128 + wave * 32 + l32] = lsum;
}

// ---------------------------------------------------------------------------
// Merge partials: common fixed scale -> plain sums.
// Task granularity is now 128 q-rows; per-row chunk count derives from the
// row's OWNING WAVE (matches the wave-level activity condition exactly).
// Grid: (b, qb, half) = 4*32*2 = 256 blocks.
// ---------------------------------------------------------------------------
__global__ __launch_bounds__(256) void merge_kernel(
    const float* __restrict__ po, const float* __restrict__ pml,
    float* __restrict__ out, int C, int chunk_keys) {
  const int bx = blockIdx.x;
  const int h  = bx & 1;
  const int qb = (bx >> 1) & 31;
  const int b  = bx >> 6;

  const int tid  = threadIdx.x;
  const int lrow = tid >> 4;          // 0..15
  const int col  = (tid & 15) * 4;    // 0..60

  const size_t base = (size_t)((b * 32 + qb) * C);

#pragma unroll
  for (int rr = 0; rr < 4; rr++) {
    const int row = h * 64 + rr * 16 + lrow;        // 0..127 within task
    const int qlast = qb * 128 + (row & ~31) + 31;  // owning wave's last q
    const int nc = min(qlast / chunk_keys + 1, C);

    float L = 0.f;
    float4 O = {0.f, 0.f, 0.f, 0.f};
    for (int cc = 0; cc < nc; cc++) {
      L += pml[(base + cc) * 128 + row];
      const float4 p = *(const float4*)&po[(base + cc) * 8192 + row * 64 + col];
      O.x += p.x; O.y += p.y; O.z += p.z; O.w += p.w;
    }
    const float inv = 1.0f / L;
    float4 res = {O.x * inv, O.y * inv, O.z * inv, O.w * inv};
    *(float4*)&out[((size_t)b * SDIM + qb * 128 + row) * 64 + col] = res;
  }
}

extern "C" void kernel_launch(void* const* d_in, const int* in_sizes, int n_in,
                              void* d_out, int out_size, void* d_ws, size_t ws_size,
                              hipStream_t stream) {
  const float* x  = (const float*)d_in[0];
  const float* Wq = (const float*)d_in[1];
  const float* Wk = (const float*)d_in[2];
  const float* Wv = (const float*)d_in[3];
  float* out = (float*)d_out;

  // ws layout: qk (4 MB) | vt (2 MB) | wb (384 KB, pad to 512 KB) | po | pml
  unsigned short* qk = (unsigned short*)d_ws;
  unsigned short* vt = qk + (size_t)2 * MTOT * 64;
  unsigned short* wb = vt + (size_t)BB * 64 * SDIM;
  const size_t po_off = 6 * 1024 * 1024 + 512 * 1024;
  float* po = (float*)((char*)d_ws + po_off);

  int C = 1;
  for (int c = 16; c >= 1; c >>= 1) {
    const size_t need = po_off + (size_t)c * (4u * 1024 * 1024)   // po
                      + (size_t)c * (64u * 1024);                 // pml
    if (need <= ws_size) { C = c; break; }
  }
  float* pml = po + (size_t)1048576 * C;   // 128C tasks * 8192 floats
  const int chunk_keys = SDIM / C;

  wcvt_kernel<<<dim3(192), dim3(256), 0, stream>>>(Wq, Wk, Wv, wb);
  proj_kernel<<<dim3(MTOT / 32), dim3(256), 0, stream>>>(x, wb, qk, vt);
  attn_kernel<<<dim3(32 * BB * C), dim3(256), 0, stream>>>(qk, vt, po, pml, C, chunk_keys);
  merge_kernel<<<dim3(BB * 32 * 2), dim3(256), 0, stream>>>(po, pml, out, C, chunk_keys);
}

// Round 2
// 149.705 us; speedup vs baseline: 1.3955x; 1.3955x over previous
//
#include <hip/hip_runtime.h>
#include <math.h>

#define SDIM 4096
#define DIN  1024
#define DOUT 64
#define BB   4
#define MTOT (BB * SDIM)   // 16384 rows
#define SMAX 12.0f         // fixed softmax max (log2 domain); true max ~8

typedef __attribute__((ext_vector_type(8))) short short8;    // 8 x bf16
typedef __attribute__((ext_vector_type(4))) float floatx4;
typedef __attribute__((ext_vector_type(16))) float floatx16;

static __device__ __forceinline__ unsigned short f2bf(float f) {
  union { float f; unsigned int u; } v; v.f = f;
  unsigned int r = v.u + 0x7fffu + ((v.u >> 16) & 1u);
  return (unsigned short)(r >> 16);
}

static __device__ __forceinline__ floatx4 mfma16(short8 a, short8 b, floatx4 c) {
  return __builtin_amdgcn_mfma_f32_16x16x32_bf16(a, b, c, 0, 0, 0);
}
static __device__ __forceinline__ floatx16 mfma32(short8 a, short8 b, floatx16 c) {
  return __builtin_amdgcn_mfma_f32_32x32x16_bf16(a, b, c, 0, 0, 0);
}
// pack two f32 -> one dword of 2 bf16 (lo = src0)
static __device__ __forceinline__ unsigned int cvtpk(float lo, float hi) {
  unsigned int r;
  asm("v_cvt_pk_bf16_f32 %0, %1, %2" : "=v"(r) : "v"(lo), "v"(hi));
  return r;
}

// ---------------------------------------------------------------------------
// W -> bf16:  wb[o][k].  q scale folds 1/sqrt(64) AND log2(e) (exp2 domain).
// ---------------------------------------------------------------------------
__global__ __launch_bounds__(256) void wcvt_kernel(
    const float* __restrict__ Wq, const float* __restrict__ Wk,
    const float* __restrict__ Wv, unsigned short* __restrict__ wb) {
  const int idx  = blockIdx.x * 256 + threadIdx.x;
  const int flat = idx * 4;
  const int m    = flat >> 16;
  const int off  = flat & 65535;
  const float* src = (m == 0) ? Wq : (m == 1) ? Wk : Wv;
  const float  s   = (m == 0) ? 0.125f * 1.44269504f : 1.0f;
  float4 v = *(const float4*)(src + off);
  ushort4 u;
  u.x = f2bf(v.x * s); u.y = f2bf(v.y * s);
  u.z = f2bf(v.z * s); u.w = f2bf(v.w * s);
  *(ushort4*)(wb + (size_t)m * 65536 + off) = u;
}

// ---------------------------------------------------------------------------
// Projection: out = x(16384x1024) @ wb^T(1024x192). Main loop unchanged
// (proven). NEW epilogue: stage results through LDS and emit FRAGMENT-MAJOR
// layouts so attn_kernel's every load is one coalesced 64-lane x 16B dwordx4:
//   Q/K frag: buf[(b*128+blk)*2048 + s*512 + lane*8 + j]
//             = elem(row = blk*32 + (lane&31), d = s*16 + (lane>>5)*8 + j)
//   V   frag: buf[(b*64+kt)*4096 + dh*2048 + s*512 + lane*8 + j]
//             = V(key = kt*64 + s*16 + (lane>>5)*8 + j, d = dh*32 + (lane&31))
// ---------------------------------------------------------------------------
__global__ __launch_bounds__(256) void proj_kernel(
    const float* __restrict__ x, const unsigned short* __restrict__ wb,
    unsigned short* __restrict__ qfb, unsigned short* __restrict__ kfb,
    unsigned short* __restrict__ vfb) {
  __shared__ __align__(16) short Xs[32][136];   // 32 x 128 bf16 (also epi Q/K)
  __shared__ __align__(16) short Vl[64][40];    // V^T tile [d][seq_local]

  const int tid  = threadIdx.x;
  const int wave = tid >> 6;
  const int lane = tid & 63;
  const int quad = lane >> 4;
  const int l16  = lane & 15;
  const int l32  = lane & 31;
  const int hl   = lane >> 5;
  const int row0 = blockIdx.x * 32;

  floatx4 acc[2][3];
#pragma unroll
  for (int i = 0; i < 2; i++)
#pragma unroll
    for (int j = 0; j < 3; j++) acc[i][j] = floatx4{0, 0, 0, 0};

  const int sr = tid >> 3;          // staging row 0..31
  const int sc = (tid & 7) * 16;    // staging col (floats) {0,16,...,112}

  float4 xa[4];
  {
    const float* xp = x + (size_t)(row0 + sr) * DIN + sc;
#pragma unroll
    for (int i = 0; i < 4; i++) xa[i] = *(const float4*)(xp + i * 4);
  }

  for (int k0 = 0; k0 < DIN; k0 += 128) {
    __syncthreads();
    short8 s0, s1;
#pragma unroll
    for (int i = 0; i < 4; i++) {
      s0[i]     = f2bf(xa[0][i]); s0[i + 4] = f2bf(xa[1][i]);
      s1[i]     = f2bf(xa[2][i]); s1[i + 4] = f2bf(xa[3][i]);
    }
    *(short8*)&Xs[sr][sc]     = s0;
    *(short8*)&Xs[sr][sc + 8] = s1;
    __syncthreads();

    if (k0 + 128 < DIN) {
      const float* xp = x + (size_t)(row0 + sr) * DIN + (k0 + 128) + sc;
#pragma unroll
      for (int i = 0; i < 4; i++) xa[i] = *(const float4*)(xp + i * 4);
    }

#pragma unroll
    for (int s = 0; s < 4; s++) {   // 4 k-steps of 32
      const short8 a0 = *(const short8*)&Xs[l16][s * 32 + quad * 8];
      const short8 a1 = *(const short8*)&Xs[16 + l16][s * 32 + quad * 8];
#pragma unroll
      for (int f = 0; f < 3; f++) {
        const int col = (wave * 3 + f) * 16 + l16;
        const short8 b =
            *(const short8*)(wb + (size_t)col * DIN + k0 + s * 32 + quad * 8);
        acc[0][f] = mfma16(a0, b, acc[0][f]);
        acc[1][f] = mfma16(a1, b, acc[1][f]);
      }
    }
  }

  // ---- epilogue: LDS re-layout -> fragment-major coalesced stores ----
  const int b4   = row0 >> 12;       // batch
  const int seq  = row0 & 4095;      // seq offset within batch
  const int qw   = seq >> 5;         // 32-row block index 0..127
  const int kt   = seq >> 6;         // 64-key tile index 0..63
  const int hsel = (seq >> 5) & 1;   // which half of the 64-key tile

  __syncthreads();                   // Xs free for reuse

  // phase A: scatter Q (cols 0..63) -> Xs[row][c]; V (cols 128..191) -> Vl
#pragma unroll
  for (int rr = 0; rr < 2; rr++)
#pragma unroll
    for (int f = 0; f < 3; f++) {
      const int c    = (wave * 3 + f) * 16 + l16;
      const int lrow = rr * 16 + quad * 4;
      if (c < 64) {
#pragma unroll
        for (int r = 0; r < 4; r++)
          Xs[lrow + r][c] = (short)f2bf(acc[rr][f][r]);
      } else if (c >= 128) {
        const int d = c - 128;
#pragma unroll
        for (int r = 0; r < 4; r++)
          Vl[d][lrow + r] = (short)f2bf(acc[rr][f][r]);
      }
    }
  __syncthreads();

  // phase B: coalesced Q-frag + V-frag stores (16B per thread each)
  {
    const int s = tid >> 6;          // 0..3
    short8 qv = *(const short8*)&Xs[l32][s * 16 + hl * 8];
    *(short8*)(qfb + (size_t)(b4 * 128 + qw) * 2048 + s * 512 + lane * 8) = qv;
  }
  {
    const int dh = tid >> 7;         // 0..1
    const int s2 = (tid >> 6) & 1;   // 0..1
    short8 vv = *(const short8*)&Vl[dh * 32 + l32][s2 * 16 + hl * 8];
    *(short8*)(vfb + (size_t)(b4 * 64 + kt) * 4096 + dh * 2048 +
               (hsel * 2 + s2) * 512 + lane * 8) = vv;
  }
  __syncthreads();

  // phase C: scatter K (cols 64..127) -> Xs
#pragma unroll
  for (int rr = 0; rr < 2; rr++)
#pragma unroll
    for (int f = 0; f < 3; f++) {
      const int c    = (wave * 3 + f) * 16 + l16;
      const int lrow = rr * 16 + quad * 4;
      if (c >= 64 && c < 128) {
#pragma unroll
        for (int r = 0; r < 4; r++)
          Xs[lrow + r][c - 64] = (short)f2bf(acc[rr][f][r]);
      }
    }
  __syncthreads();

  // phase D: coalesced K-frag store
  {
    const int s = tid >> 6;
    short8 kv = *(const short8*)&Xs[l32][s * 16 + hl * 8];
    *(short8*)(kfb + (size_t)(b4 * 128 + qw) * 2048 + s * 512 + lane * 8) = kv;
  }
}

// ---------------------------------------------------------------------------
// Flash attention. Block = (b, 32 q-rows); 4 waves split the causal key range
// (wave w takes 64-key tiles t = w, w+4, ...). All loads are coalesced
// frag-major dwordx4 from L2. Swapped QK^T -> in-register softmax; P
// redistributed via cvt_pk + permlane32_swap (R1, verified). Fixed-SMAX
// exp2-domain softmax -> wave partials combine by PLAIN SUM: one LDS
// reduction at the end writes the FINAL output (no po/pml/merge).
// Grid: 512 blocks = 128 qw x 4 b, interleaved big/small for CU balance.
// ---------------------------------------------------------------------------
__global__ __launch_bounds__(256) void attn_kernel(
    const unsigned short* __restrict__ qfb, const unsigned short* __restrict__ kfb,
    const unsigned short* __restrict__ vfb, float* __restrict__ out) {
  __shared__ float Ol[4][32][68];
  __shared__ float Ls[4][32];

  const int tid  = threadIdx.x;
  const int wave = tid >> 6;
  const int lane = tid & 63;
  const int l32  = lane & 31;
  const int hl   = lane >> 5;

  const int bx = blockIdx.x;
  const int u  = bx >> 2;
  const int b  = bx & 3;
  const int qw = (u & 1) ? (u >> 1) : (127 - (u >> 1));  // pair big with small
  const int wq0 = qw * 32;
  const int nt  = (qw >> 1) + 1;     // 64-key tiles covering keys 0..wq0+31

  // Q B-frags (col = l32 = q, k = hl*8+j), resident whole kernel
  short8 qf[4];
  {
    const unsigned short* qp = qfb + (size_t)(b * 128 + qw) * 2048 + lane * 8;
#pragma unroll
    for (int s = 0; s < 4; s++) qf[s] = *(const short8*)(qp + s * 512);
  }

  const unsigned short* kbase = kfb + (size_t)b * 128 * 2048 + lane * 8;
  const unsigned short* vbase = vfb + (size_t)b * 64 * 4096 + lane * 8;

  floatx16 o0, o1;
#pragma unroll
  for (int r = 0; r < 16; r++) { o0[r] = 0.f; o1[r] = 0.f; }
  float ls0 = 0.f, ls1 = 0.f, ls2 = 0.f, ls3 = 0.f;

  for (int t = wave; t < nt; t += 4) {
    const int k0 = t * 64;
    const unsigned short* kp = kbase + (size_t)t * 4096;
    const unsigned short* vp = vbase + (size_t)t * 4096;

    short8 kf[8];
#pragma unroll
    for (int sub = 0; sub < 2; sub++)
#pragma unroll
      for (int s = 0; s < 4; s++)
        kf[sub * 4 + s] = *(const short8*)(kp + sub * 2048 + s * 512);

    short8 vf[8];
#pragma unroll
    for (int dh = 0; dh < 2; dh++)
#pragma unroll
      for (int s = 0; s < 4; s++)
        vf[dh * 4 + s] = *(const short8*)(vp + dh * 2048 + s * 512);

    // ---- S^T - SMAX = K Q^T + (-SMAX) ----
    floatx16 s0, s1;
#pragma unroll
    for (int r = 0; r < 16; r++) { s0[r] = -SMAX; s1[r] = -SMAX; }
#pragma unroll
    for (int s = 0; s < 4; s++) s0 = mfma32(kf[s], qf[s], s0);
#pragma unroll
    for (int s = 0; s < 4; s++) s1 = mfma32(kf[4 + s], qf[s], s1);

    // causal mask: key = k0 + sub*32 + (r&3) + 8*(r>>2) + 4*hl; q = wq0 + l32
    if (k0 + 63 > wq0) {
      const int dq = k0 + hl * 4 - wq0 - l32;
#pragma unroll
      for (int r = 0; r < 16; r++) {
        const int kl = (r & 3) + 8 * (r >> 2);
        if (dq + kl > 0)      s0[r] = -INFINITY;
        if (dq + kl + 32 > 0) s1[r] = -INFINITY;
      }
    }

    // ---- p = exp2(s - SMAX); per-lane partial denominator ----
#pragma unroll
    for (int r = 0; r < 16; r++) { s0[r] = exp2f(s0[r]); s1[r] = exp2f(s1[r]); }
#pragma unroll
    for (int r = 0; r < 4; r++) {
      ls0 += s0[r]      + s1[r];
      ls1 += s0[r + 4]  + s1[r + 4];
      ls2 += s0[r + 8]  + s1[r + 8];
      ls3 += s0[r + 12] + s1[r + 12];
    }

    // ---- P (C-layout) -> PV A-frags via cvt_pk + permlane32_swap ----
    short8 pa[4];
#pragma unroll
    for (int sb = 0; sb < 2; sb++) {       // S^T sub-tile (keys sb*32..+31)
      const floatx16 sp = sb ? s1 : s0;
#pragma unroll
      for (int ss = 0; ss < 2; ss++) {     // 16-key step within sub-tile
        const int r0 = ss * 8;
        unsigned int x0 = cvtpk(sp[r0 + 0], sp[r0 + 1]);
        unsigned int y0 = cvtpk(sp[r0 + 4], sp[r0 + 5]);
        unsigned int x1 = cvtpk(sp[r0 + 2], sp[r0 + 3]);
        unsigned int y1 = cvtpk(sp[r0 + 6], sp[r0 + 7]);
        asm("v_permlane32_swap_b32 %0, %1" : "+v"(x0), "+v"(y0));
        asm("v_permlane32_swap_b32 %0, %1" : "+v"(x1), "+v"(y1));
        union { unsigned int u[4]; short8 s; } pu;
        pu.u[0] = x0; pu.u[1] = x1; pu.u[2] = y0; pu.u[3] = y1;
        pa[sb * 2 + ss] = pu.s;
      }
    }

    // ---- O += P V ----
#pragma unroll
    for (int s = 0; s < 4; s++) {
      o0 = mfma32(pa[s], vf[s],     o0);
      o1 = mfma32(pa[s], vf[4 + s], o1);
    }
  }

  // ---- per-wave denominator (q = l32 in both halves) ----
  float lsum = (ls0 + ls1) + (ls2 + ls3);
  lsum += __shfl_xor(lsum, 32);

  // ---- cross-wave reduction in LDS; write FINAL output ----
#pragma unroll
  for (int r = 0; r < 16; r++) {
    const int qr = (r & 3) + 8 * (r >> 2) + 4 * hl;   // q-local 0..31
    Ol[wave][qr][l32]      = o0[r];
    Ol[wave][qr][32 + l32] = o1[r];
  }
  if (hl == 0) Ls[wave][l32] = lsum;
  __syncthreads();

  const int q  = tid >> 3;          // 0..31
  const int dg = (tid & 7) * 8;     // 0..56
  const float L   = Ls[0][q] + Ls[1][q] + Ls[2][q] + Ls[3][q];
  const float inv = 1.0f / L;
  float4 a = {0.f, 0.f, 0.f, 0.f}, c2 = {0.f, 0.f, 0.f, 0.f};
#pragma unroll
  for (int w = 0; w < 4; w++) {
    const float4 pa4 = *(const float4*)&Ol[w][q][dg];
    const float4 pb4 = *(const float4*)&Ol[w][q][dg + 4];
    a.x  += pa4.x; a.y  += pa4.y; a.z  += pa4.z; a.w  += pa4.w;
    c2.x += pb4.x; c2.y += pb4.y; c2.z += pb4.z; c2.w += pb4.w;
  }
  float* op = out + ((size_t)b * SDIM + wq0 + q) * 64 + dg;
  float4 r0v = {a.x * inv, a.y * inv, a.z * inv, a.w * inv};
  float4 r1v = {c2.x * inv, c2.y * inv, c2.z * inv, c2.w * inv};
  *(float4*)op       = r0v;
  *(float4*)(op + 4) = r1v;
}

extern "C" void kernel_launch(void* const* d_in, const int* in_sizes, int n_in,
                              void* d_out, int out_size, void* d_ws, size_t ws_size,
                              hipStream_t stream) {
  const float* x  = (const float*)d_in[0];
  const float* Wq = (const float*)d_in[1];
  const float* Wk = (const float*)d_in[2];
  const float* Wv = (const float*)d_in[3];
  float* out = (float*)d_out;

  // ws layout: q_frag (2MB) | k_frag (2MB) | v_frag (2MB) | wb (384KB)
  unsigned short* qfb = (unsigned short*)d_ws;
  unsigned short* kfb = qfb + (size_t)1048576;
  unsigned short* vfb = kfb + (size_t)1048576;
  unsigned short* wb  = vfb + (size_t)1048576;

  wcvt_kernel<<<dim3(192), dim3(256), 0, stream>>>(Wq, Wk, Wv, wb);
  proj_kernel<<<dim3(MTOT / 32), dim3(256), 0, stream>>>(x, wb, qfb, kfb, vfb);
  attn_kernel<<<dim3(512), dim3(256), 0, stream>>>(qfb, kfb, vfb, out);
}